// Round 8
// baseline (131.706 us; speedup 1.0000x reference)
//
#include <hip/hip_runtime.h>
#include <hip/hip_bf16.h>
#include <cstdint>

#define NB 2
#define LL 384
#define DIN 256
#define DE 128
#define NH 8
#define DH 32
#define HD 256          // NH*DH
#define TJ 64           // j-tile rows (was 32: halves barrier/softmax phases)
#define NTILES (LL / TJ)
#define SCALE 0.17677669529663687f

typedef __attribute__((ext_vector_type(8))) short bf16x8;
typedef __attribute__((ext_vector_type(4))) float f32x4;

static __device__ __forceinline__ unsigned short f2bf(float f) {
    uint32_t u = __builtin_bit_cast(uint32_t, f);
    u += 0x7FFF + ((u >> 16) & 1);          // RNE
    return (unsigned short)(u >> 16);
}
static __device__ __forceinline__ float bf2f(unsigned short u) {
    return __builtin_bit_cast(float, (uint32_t)u << 16);
}
static __device__ __forceinline__ float getf4(const float4& v, int k) {
    return k == 0 ? v.x : k == 1 ? v.y : k == 2 ? v.z : v.w;
}
static __device__ __forceinline__ bf16x8 pack8(const float4& a, const float4& b) {
    bf16x8 p;
    p[0]=(short)f2bf(a.x); p[1]=(short)f2bf(a.y); p[2]=(short)f2bf(a.z); p[3]=(short)f2bf(a.w);
    p[4]=(short)f2bf(b.x); p[5]=(short)f2bf(b.y); p[6]=(short)f2bf(b.z); p[7]=(short)f2bf(b.w);
    return p;
}

// ---------------- prep_we: We^T -> bf16 (HD x DE, n-major) ----------------
__global__ __launch_bounds__(128) void prep_we(const float* __restrict__ We,
                                               unsigned short* __restrict__ WeT) {
    const int n = blockIdx.x;    // 0..255
    const int k = threadIdx.x;   // 0..127
    WeT[n * DE + k] = f2bf(We[(size_t)k * HD + n]);
}

// ---------------- proj: q/k -> bf16, v/u -> fp32 ----------------
__global__ __launch_bounds__(256) void proj_kernel(
    const float* __restrict__ node,
    const float* __restrict__ Wq, const float* __restrict__ bq,
    const float* __restrict__ Wk, const float* __restrict__ bk,
    const float* __restrict__ Wv, const float* __restrict__ bv,
    const float* __restrict__ Wu, const float* __restrict__ bu,
    unsigned short* __restrict__ qb16, unsigned short* __restrict__ kb16,
    float* __restrict__ vb, float* __restrict__ ub)
{
    __shared__ __align__(16) float rows[4][DIN];
    const int t  = threadIdx.x;
    const int r0 = blockIdx.x * 4;

    #pragma unroll
    for (int r = 0; r < 4; ++r)
        rows[r][t] = node[(size_t)(r0 + r) * DIN + t];
    __syncthreads();

    float aq[4], ak[4], av[4], au[4];
    {
        const float vq = bq[t], vk = bk[t], vv = bv[t], vu = bu[t];
        #pragma unroll
        for (int r = 0; r < 4; ++r) { aq[r] = vq; ak[r] = vk; av[r] = vv; au[r] = vu; }
    }

    for (int f4 = 0; f4 < DIN / 4; ++f4) {
        float4 xv[4];
        #pragma unroll
        for (int r = 0; r < 4; ++r)
            xv[r] = *(const float4*)&rows[r][f4 * 4];
        #pragma unroll
        for (int k = 0; k < 4; ++k) {
            const int f = f4 * 4 + k;
            const float wq = Wq[(size_t)f * HD + t];
            const float wk = Wk[(size_t)f * HD + t];
            const float wv = Wv[(size_t)f * HD + t];
            const float wu = Wu[(size_t)f * HD + t];
            #pragma unroll
            for (int r = 0; r < 4; ++r) {
                const float x = getf4(xv[r], k);
                aq[r] += x * wq; ak[r] += x * wk; av[r] += x * wv; au[r] += x * wu;
            }
        }
    }

    #pragma unroll
    for (int r = 0; r < 4; ++r) {
        const size_t o = (size_t)(r0 + r) * HD + t;
        qb16[o] = f2bf(aq[r]); kb16[o] = f2bf(ak[r]);
        vb[o] = av[r]; ub[o] = au[r];
    }
}

// ---------------- vt: v (fp32, j-major) -> vT (bf16, col-major) ----------------
__global__ __launch_bounds__(256) void vt_kernel(const float* __restrict__ vb,
                                                 unsigned short* __restrict__ vT) {
    __shared__ float tile[64][65];
    int blk = blockIdx.x;
    const int b  = blk / 24; blk %= 24;
    const int jt = blk / 4;
    const int ct = blk % 4;
    const int j0 = jt * 64, c0 = ct * 64;
    const int t  = threadIdx.x;
    const int c  = t & 63, j4 = t >> 6;
    #pragma unroll
    for (int rr = 0; rr < 16; ++rr) {
        const int j = j4 + 4 * rr;
        tile[j][c] = vb[(size_t)(b * LL + j0 + j) * HD + c0 + c];
    }
    __syncthreads();
    const int jj = t & 63, c4 = t >> 6;
    #pragma unroll
    for (int rr = 0; rr < 16; ++rr) {
        const int cc = c4 + 4 * rr;
        vT[(size_t)(b * HD + c0 + cc) * LL + j0 + jj] = f2bf(tile[jj][cc]);
    }
}

// ---------------- qk: logit_pre[b,h,i,j] = SCALE*(q.k) - 1e9*(1-mask) ----------------
__global__ __launch_bounds__(256) void qk_kernel(
    const unsigned short* __restrict__ qb16, const unsigned short* __restrict__ kb16,
    const float* __restrict__ mask, float* __restrict__ logit_pre)
{
    int idx = blockIdx.x;
    const int jt = idx % 6; idx /= 6;
    const int it = idx % 6; idx /= 6;
    const int h  = idx % NH;
    const int b  = idx / NH;
    const int t    = threadIdx.x;
    const int lane = t & 63;
    const int w    = t >> 6;
    const int lid  = lane & 15;
    const int g    = lane >> 4;
    const int i0 = it * 64 + w * 16;
    const int j0 = jt * 64;

    const bf16x8 afr = *(const bf16x8*)&qb16[(size_t)(b * LL + i0 + lid) * HD + h * DH + g * 8];
    f32x4 acc[4];
    #pragma unroll
    for (int jj = 0; jj < 4; ++jj) {
        const bf16x8 bfrg = *(const bf16x8*)&kb16[(size_t)(b * LL + j0 + jj * 16 + lid) * HD + h * DH + g * 8];
        acc[jj] = __builtin_amdgcn_mfma_f32_16x16x32_bf16(afr, bfrg, (f32x4){0.f,0.f,0.f,0.f}, 0, 0, 0);
    }
    #pragma unroll
    for (int jj = 0; jj < 4; ++jj) {
        #pragma unroll
        for (int r = 0; r < 4; ++r) {
            const int i = i0 + 4 * g + r;
            const int j = j0 + jj * 16 + lid;
            const float lg = SCALE * acc[jj][r]
                           + (1.0f - mask[(size_t)(b * LL + i) * LL + j]) * -1e9f;
            logit_pre[((size_t)(b * NH + h) * LL + i) * LL + j] = lg;
        }
    }
}

// ---------------- attn: MFMA edge-embed + fused attention ----------------
// grid = B*L blocks (one per (b,i)), 512 threads = 8 waves, wave w <-> head w.
// TJ=64: 6 tile phases (vs 12). All 64 lanes hold DISTINCT j after the 4-level
// butterfly (xor8->mm bit1, xor4->mm bit0, xor2->r bit1, xor1->r bit0), so no
// duplicate-slot 0.5 factor. setprio(1) around the MFMA cluster (T5).
__global__ __launch_bounds__(512, 4) void attn_kernel(
    const float* __restrict__ edge,            // (B,L,L,DE)
    const unsigned short* __restrict__ WeT,    // (HD, DE) bf16 n-major
    const float* __restrict__ logit_pre,       // (B,NH,L,L) scaled+masked qk
    const unsigned short* __restrict__ qb16,   // (B,L,HD) bf16
    const unsigned short* __restrict__ vT,     // (B,HD,L) bf16 col-major
    const float* __restrict__ ub,
    float* __restrict__ out)
{
    const int t    = threadIdx.x;
    const int lane = t & 63;
    const int w    = t >> 6;        // wave id = head 0..7
    const int lid  = lane & 15;
    const int g    = lane >> 4;
    const int wb   = w * DH;        // head's first col
    const int bi   = blockIdx.x;
    const int b    = bi / LL;
    const int ii   = bi % LL;

    __shared__ __align__(16) unsigned short Es[2][TJ * DE];   // 32 KiB

    const float* efbase = edge + (size_t)bi * LL * DE;
    const float* lpre   = logit_pre + ((size_t)(b * NH + w) * LL + ii) * LL;
    const unsigned short* vTb = vT + (size_t)b * HD * LL;

    // persistent We^T fragments: this head's 32 cols (2 col-tiles)
    bf16x8 bfr[2][4];
    #pragma unroll
    for (int ct = 0; ct < 2; ++ct)
        #pragma unroll
        for (int kt = 0; kt < 4; ++kt)
            bfr[ct][kt] = *(const bf16x8*)&WeT[(size_t)(wb + ct * 16 + lid) * DE + kt * 32 + g * 8];

    float qf[2];
    #pragma unroll
    for (int ct = 0; ct < 2; ++ct)
        qf[ct] = bf2f(qb16[(size_t)bi * HD + wb + ct * 16 + lid]) * SCALE;

    // staging: thread t stages rows sr and sr+32, chunk ci (8 floats -> one bf16x8)
    const int sr = t >> 4;          // 0..31
    const int ci = t & 15;          // 0..15
    const int wchunk = (ci ^ (sr & 15)) << 3;   // swizzled element offset (same for sr+32)

    const int jl_self = ((lid >> 2) & 3) * 16 + 4 * g + (lid & 3);

    float m_run = -3e38f, l_run = 0.0f;
    float out_p[2] = {0.f, 0.f};

    // prologue: stage tile 0 (rows sr, sr+32)
    #pragma unroll
    for (int q = 0; q < 2; ++q) {
        const int row = sr + 32 * q;
        const float* src = efbase + (size_t)row * DE + ci * 8;
        const float4 x0 = ((const float4*)src)[0];
        const float4 x1 = ((const float4*)src)[1];
        *(bf16x8*)&Es[0][row * DE + wchunk] = pack8(x0, x1);
    }

    for (int tile = 0; tile < NTILES; ++tile) {
        const int j0  = tile * TJ;
        const int cur = tile & 1;
        const unsigned short* Ecur = Es[cur];
        __syncthreads();   // Es[cur] visible; prior reads of Es[cur^1] done

        // issue next tile's edge loads
        const bool have_next = (tile + 1 < NTILES);
        float4 nx[2][2];
        if (have_next) {
            #pragma unroll
            for (int q = 0; q < 2; ++q) {
                const float* src = efbase + (size_t)(j0 + TJ + sr + 32 * q) * DE + ci * 8;
                nx[q][0] = ((const float4*)src)[0];
                nx[q][1] = ((const float4*)src)[1];
            }
        }
        // issue this tile's qk-logit and v loads
        const float qkm = lpre[j0 + jl_self];
        ushort4 vld[2][4];
        #pragma unroll
        for (int ct = 0; ct < 2; ++ct)
            #pragma unroll
            for (int mm = 0; mm < 4; ++mm)
                vld[ct][mm] = *(const ushort4*)&vTb[(size_t)(wb + ct * 16 + lid) * LL + j0 + mm * 16 + 4 * g];

        // e-tile MFMA: acc[mm][ct], rows mm*16+lid
        f32x4 acc[4][2];
        #pragma unroll
        for (int mm = 0; mm < 4; ++mm)
            #pragma unroll
            for (int ct = 0; ct < 2; ++ct)
                acc[mm][ct] = (f32x4){0.f, 0.f, 0.f, 0.f};

        __builtin_amdgcn_s_setprio(1);
        #pragma unroll
        for (int kt = 0; kt < 4; ++kt) {
            const int ch = kt * 4 + g;
            bf16x8 a[4];
            #pragma unroll
            for (int mm = 0; mm < 4; ++mm)
                a[mm] = *(const bf16x8*)&Ecur[(mm * 16 + lid) * DE + ((ch ^ lid) << 3)];
            #pragma unroll
            for (int ct = 0; ct < 2; ++ct)
                #pragma unroll
                for (int mm = 0; mm < 4; ++mm)
                    acc[mm][ct] = __builtin_amdgcn_mfma_f32_16x16x32_bf16(a[mm], bfr[ct][kt], acc[mm][ct], 0, 0, 0);
        }
        __builtin_amdgcn_s_setprio(0);

        // qe logits: plog[mm*4+rg], summed over this lane's 2 cols
        float plog[16];
        #pragma unroll
        for (int mm = 0; mm < 4; ++mm)
            #pragma unroll
            for (int rg = 0; rg < 4; ++rg)
                plog[mm * 4 + rg] = acc[mm][0][rg] * qf[0] + acc[mm][1][rg] * qf[1];

        // reduce over 16 lids with 4 split levels: xor8(mm b1), xor4(mm b0), xor2(r b1), xor1(r b0)
        float v8[8];
        {
            const bool hi = (lane & 8) != 0;
            #pragma unroll
            for (int k = 0; k < 8; ++k) {
                const float keep = hi ? plog[8 + k] : plog[k];
                const float send = hi ? plog[k] : plog[8 + k];
                v8[k] = keep + __shfl_xor(send, 8);
            }
        }
        float v4[4];
        {
            const bool hi = (lane & 4) != 0;
            #pragma unroll
            for (int r = 0; r < 4; ++r) {
                const float keep = hi ? v8[4 + r] : v8[r];
                const float send = hi ? v8[r] : v8[4 + r];
                v4[r] = keep + __shfl_xor(send, 4);
            }
        }
        float v2[2];
        {
            const bool hi = (lane & 2) != 0;
            #pragma unroll
            for (int c2 = 0; c2 < 2; ++c2) {
                const float keep = hi ? v4[2 + c2] : v4[c2];
                const float send = hi ? v4[c2] : v4[2 + c2];
                v2[c2] = keep + __shfl_xor(send, 2);
            }
        }
        float lgv;
        {
            const bool hi = (lane & 1) != 0;
            const float keep = hi ? v2[1] : v2[0];
            const float send = hi ? v2[0] : v2[1];
            lgv = keep + __shfl_xor(send, 1);
        }
        // lane holds logit for its unique jl_self (64 distinct j)
        const float lg = lgv + qkm;

        // wave-local online softmax (no duplicate slots)
        float mt = lg;
        #pragma unroll
        for (int off = 1; off < 64; off <<= 1) mt = fmaxf(mt, __shfl_xor(mt, off));
        const float mn = fmaxf(m_run, mt);
        const float p  = __expf(lg - mn);
        float ps = p;
        #pragma unroll
        for (int off = 1; off < 64; off <<= 1) ps += __shfl_xor(ps, off);
        const float fs = __expf(m_run - mn);
        l_run = l_run * fs + ps;
        m_run = mn;

        // distribute p: slot (mm,rg) for this lane's g lives at lane (lane&48) + mm*4+rg
        float pp[16];
        #pragma unroll
        for (int mm = 0; mm < 4; ++mm)
            #pragma unroll
            for (int rg = 0; rg < 4; ++rg)
                pp[mm * 4 + rg] = __shfl(p, (lane & 48) + mm * 4 + rg);

        // PV: out_p[ct] = out_p[ct]*fs + sum p*(v+e)
        out_p[0] *= fs; out_p[1] *= fs;
        #pragma unroll
        for (int ct = 0; ct < 2; ++ct)
            #pragma unroll
            for (int mm = 0; mm < 4; ++mm) {
                const ushort4 vv = vld[ct][mm];
                out_p[ct] += pp[mm * 4 + 0] * (bf2f(vv.x) + acc[mm][ct][0]);
                out_p[ct] += pp[mm * 4 + 1] * (bf2f(vv.y) + acc[mm][ct][1]);
                out_p[ct] += pp[mm * 4 + 2] * (bf2f(vv.z) + acc[mm][ct][2]);
                out_p[ct] += pp[mm * 4 + 3] * (bf2f(vv.w) + acc[mm][ct][3]);
            }

        // stage-write next tile (loads issued at loop top; latency hidden)
        if (have_next) {
            #pragma unroll
            for (int q = 0; q < 2; ++q)
                *(bf16x8*)&Es[cur ^ 1][(sr + 32 * q) * DE + wchunk] = pack8(nx[q][0], nx[q][1]);
        }
    }

    // epilogue: reduce over g groups, write
    #pragma unroll
    for (int ct = 0; ct < 2; ++ct) {
        out_p[ct] += __shfl_xor(out_p[ct], 16);
        out_p[ct] += __shfl_xor(out_p[ct], 32);
    }
    if (lane < 16) {
        const float inv = 1.0f / l_run;
        #pragma unroll
        for (int ct = 0; ct < 2; ++ct) {
            const int col = wb + ct * 16 + lane;
            out[(size_t)bi * HD + col] = ub[(size_t)bi * HD + col] + out_p[ct] * inv;
        }
    }
}

extern "C" void kernel_launch(void* const* d_in, const int* in_sizes, int n_in,
                              void* d_out, int out_size, void* d_ws, size_t ws_size,
                              hipStream_t stream) {
    const float* node = (const float*)d_in[0];
    const float* edge = (const float*)d_in[1];
    const float* mask = (const float*)d_in[2];
    const float* Wq   = (const float*)d_in[3];
    const float* bq   = (const float*)d_in[4];
    const float* Wk   = (const float*)d_in[5];
    const float* bk   = (const float*)d_in[6];
    const float* Wv   = (const float*)d_in[7];
    const float* bv   = (const float*)d_in[8];
    const float* We   = (const float*)d_in[9];
    const float* Wu   = (const float*)d_in[10];
    const float* bu   = (const float*)d_in[11];
    float* out = (float*)d_out;

    const size_t rowsz = (size_t)NB * LL * HD;            // 196608
    float* ws   = (float*)d_ws;
    float* vb   = ws;
    float* ubuf = vb + rowsz;
    float* lpre = ubuf + rowsz;                           // NB*NH*LL*LL = 2359296
    unsigned short* us   = (unsigned short*)(lpre + (size_t)NB * NH * LL * LL);
    unsigned short* WeT  = us;                            // HD*DE = 32768
    unsigned short* qb16 = WeT + (size_t)HD * DE;
    unsigned short* kb16 = qb16 + rowsz;
    unsigned short* vT   = kb16 + rowsz;

    hipLaunchKernelGGL(prep_we, dim3(HD), dim3(DE), 0, stream, We, WeT);
    hipLaunchKernelGGL(proj_kernel, dim3(NB * LL / 4), dim3(256), 0, stream,
                       node, Wq, bq, Wk, bk, Wv, bv, Wu, bu, qb16, kb16, vb, ubuf);
    hipLaunchKernelGGL(vt_kernel, dim3(NB * (LL / 64) * (HD / 64)), dim3(256), 0, stream,
                       vb, vT);
    hipLaunchKernelGGL(qk_kernel, dim3(NB * NH * (LL / 64) * (LL / 64)), dim3(256), 0, stream,
                       qb16, kb16, mask, lpre);
    hipLaunchKernelGGL(attn_kernel, dim3(NB * LL), dim3(512), 0, stream,
                       edge, WeT, lpre, qb16, vT, ubuf, out);
}